// Round 1
// baseline (381.190 us; speedup 1.0000x reference)
//
#include <hip/hip_runtime.h>
#include <stdint.h>

#define NB 8
#define NP 100
#define NT 500
#define NV 128
#define NBP 800   // NB*NP

// ---------------- Threefry-2x32, key = (0,1) (jax.random.key(1)) ----------------
__device__ __forceinline__ void threefry01(uint32_t x0, uint32_t x1,
                                           uint32_t& o0, uint32_t& o1) {
  const uint32_t k0 = 0u, k1 = 1u;
  const uint32_t k2 = 0x1BD11BDAu ^ k0 ^ k1;  // 0x1BD11BDB
  x0 += k0; x1 += k1;
#define TF_R(r) { x0 += x1; x1 = (x1 << (r)) | (x1 >> (32 - (r))); x1 ^= x0; }
  TF_R(13) TF_R(15) TF_R(26) TF_R(6)
  x0 += k1; x1 += k2 + 1u;
  TF_R(17) TF_R(29) TF_R(16) TF_R(24)
  x0 += k2; x1 += k0 + 2u;
  TF_R(13) TF_R(15) TF_R(26) TF_R(6)
  x0 += k0; x1 += k1 + 3u;
  TF_R(17) TF_R(29) TF_R(16) TF_R(24)
  x0 += k1; x1 += k2 + 4u;
  TF_R(13) TF_R(15) TF_R(26) TF_R(6)
  x0 += k2; x1 += k0 + 5u;
#undef TF_R
  o0 = x0; o1 = x1;
}

// bits -> uniform(1e-6, 1-1e-6) exactly as jax._src.random._uniform (f32)
__device__ __forceinline__ float bits_to_u(uint32_t bits) {
  const float minv = 1e-6f;
  const float maxv = (float)(1.0 - 1e-6);
  const float span = maxv - minv;
  float f = __uint_as_float((bits >> 9) | 0x3f800000u) - 1.0f;
  return fmaxf(minv, f * span + minv);
}

__device__ __forceinline__ float gumbel_from_bits(uint32_t bits) {
  float u = bits_to_u(bits);
  return -__logf(-__logf(u));   // precision only affects argmax near-ties
}

// ---------------- Kernel 1: Gumbel sampling + argmax over V=128 ----------------
// grid (NB, NT), block 256 (4 waves); wave handles p = wave, wave+4, ...
// writes tok[t*NBP+bp] (chosen token) and lp[t*NBP+bp] (emissions at token)
__global__ __launch_bounds__(256) void k_sample(
    const float* __restrict__ em, const int* __restrict__ elen,
    int* __restrict__ tok, float* __restrict__ lp) {
  const int b = blockIdx.x;
  const int t = blockIdx.y;
  if (t >= elen[b]) return;  // frames beyond length are never consumed
  __shared__ float e[NV];
  const int tid = threadIdx.x;
  if (tid < NV) e[tid] = em[(b * NT + t) * NV + tid];
  __syncthreads();
  const int wave = tid >> 6, lane = tid & 63;
  const float e_lo = e[lane], e_hi = e[lane + 64];
  for (int p = wave; p < NP; p += 4) {
    const uint32_t base = (uint32_t)(((b * NP + p) * NT + t) * NV);
    // partitionable threefry: bits[i] = low output of threefry(key, i>>32, i)
    uint32_t d0, lo_a, d1, lo_b;
    threefry01(0u, base + (uint32_t)lane, d0, lo_a);
    threefry01(0u, base + (uint32_t)lane + 64u, d1, lo_b);
    float v0 = fmaf(e_lo, 0.5f, gumbel_from_bits(lo_a));
    float v1 = fmaf(e_hi, 0.5f, gumbel_from_bits(lo_b));
    float bv; int bi;
    if (v1 > v0) { bv = v1; bi = lane + 64; } else { bv = v0; bi = lane; }
    // wave argmax, first-index tiebreak (matches jnp.argmax)
    for (int off = 1; off < 64; off <<= 1) {
      float ov = __shfl_xor(bv, off);
      int   oi = __shfl_xor(bi, off);
      if (ov > bv || (ov == bv && oi < bi)) { bv = ov; bi = oi; }
    }
    if (lane == 0) {
      const int bp = b * NP + p;
      tok[t * NBP + bp] = bi;
      lp[t * NBP + bp] = e[bi];
    }
  }
}

// ---------------- Kernel 2: CTC collapse + Myers bit-parallel edit distance ----
// one lane per path (bp); 13 blocks x 64. Peq per-b (2 b's per block) in LDS.
__global__ __launch_bounds__(64) void k_dp(
    const int* __restrict__ tok, const float* __restrict__ lp,
    const int* __restrict__ elen, const int* __restrict__ labels,
    const int* __restrict__ llen,
    float* __restrict__ wer, float* __restrict__ logp_out) {
  __shared__ uint64_t peq[2][NV][2];  // [b_local][token][word], 4 KB
  const int lane = threadIdx.x;
  const int bp = blockIdx.x * 64 + lane;
  const int bbase = (blockIdx.x * 64) / NP;
  for (int i = lane; i < 2 * NV * 2; i += 64) ((uint64_t*)peq)[i] = 0ull;
  __syncthreads();
  if (lane < 2) {
    const int b = bbase + lane;
    if (b < NB) {
      const int m = llen[b];
      for (int i = 0; i < m; i++) {
        const int c = labels[b * NP + i];  // L == NP == 100
        peq[lane][c][i >> 6] |= (1ull << (i & 63));
      }
    }
  }
  __syncthreads();
  const bool active = (bp < NBP);
  const int bpc = active ? bp : (NBP - 1);
  const int b = bpc / NP;
  const int blocal = b - bbase;
  const int myel = elen[b];
  const int m = llen[b];  // ref_len in [80,100]
  uint64_t Pv0 = ~0ull, Pv1 = ~0ull, Mv0 = 0ull, Mv1 = 0ull;
  int score = m;
  const int hw = (m - 1) >> 6;
  const uint64_t hmask = 1ull << ((m - 1) & 63);
  float logp = 0.0f;
  int prev = -1;
  for (int t = 0; t < NT; t++) {
    const int c = tok[t * NBP + bpc];     // coalesced across lanes
    const float l = lp[t * NBP + bpc];
    const bool valid = (t < myel);
    const bool kept = valid && (c != 0) && (c != prev);
    if (valid) { logp += l; prev = c; }
    if (kept) {
      const uint64_t Eq0 = peq[blocal][c][0], Eq1 = peq[blocal][c][1];
      const uint64_t Xv0 = Eq0 | Mv0, Xv1 = Eq1 | Mv1;
      const uint64_t EP0 = Eq0 & Pv0, EP1 = Eq1 & Pv1;
      const uint64_t s0 = EP0 + Pv0;
      const uint64_t s1 = EP1 + Pv1 + (s0 < EP0 ? 1ull : 0ull);
      const uint64_t Xh0 = (s0 ^ Pv0) | Eq0;
      const uint64_t Xh1 = (s1 ^ Pv1) | Eq1;
      const uint64_t Ph0 = Mv0 | ~(Xh0 | Pv0);
      const uint64_t Ph1 = Mv1 | ~(Xh1 | Pv1);
      const uint64_t Mh0 = Pv0 & Xh0, Mh1 = Pv1 & Xh1;
      const uint64_t PhH = hw ? Ph1 : Ph0;
      const uint64_t MhH = hw ? Mh1 : Mh0;
      score += (int)((PhH & hmask) != 0) - (int)((MhH & hmask) != 0);
      const uint64_t nPh1 = (Ph1 << 1) | (Ph0 >> 63);
      const uint64_t nPh0 = (Ph0 << 1) | 1ull;   // dp[0][j] = j boundary
      const uint64_t nMh1 = (Mh1 << 1) | (Mh0 >> 63);
      const uint64_t nMh0 = (Mh0 << 1);
      Pv0 = nMh0 | ~(Xv0 | nPh0);
      Pv1 = nMh1 | ~(Xv1 | nPh1);
      Mv0 = nPh0 & Xv0;
      Mv1 = nPh1 & Xv1;
    }
  }
  if (active) { wer[bp] = (float)score; logp_out[bp] = logp; }
}

// ---------------- Kernel 3: per-b softmax over P, expected WER, mean -----------
__global__ __launch_bounds__(512) void k_final(
    const float* __restrict__ wer, const float* __restrict__ logp,
    float* __restrict__ out) {
  __shared__ float partial[NB];
  const int w = threadIdx.x >> 6, lane = threadIdx.x & 63;
  const int base = w * NP;
  float l0 = (lane < NP) ? logp[base + lane] : -1e30f;
  float l1 = (lane + 64 < NP) ? logp[base + lane + 64] : -1e30f;
  float mx = fmaxf(l0, l1);
  for (int off = 1; off < 64; off <<= 1) mx = fmaxf(mx, __shfl_xor(mx, off));
  const float e0 = (lane < NP) ? __expf(l0 - mx) : 0.0f;
  const float e1 = (lane + 64 < NP) ? __expf(l1 - mx) : 0.0f;
  const float w0 = (lane < NP) ? wer[base + lane] : 0.0f;
  const float w1 = (lane + 64 < NP) ? wer[base + lane + 64] : 0.0f;
  float s = e0 + e1;
  float a = e0 * w0 + e1 * w1;
  for (int off = 1; off < 64; off <<= 1) {
    s += __shfl_xor(s, off);
    a += __shfl_xor(a, off);
  }
  if (lane == 0) partial[w] = a / s;
  __syncthreads();
  if (threadIdx.x == 0) {
    float tot = 0.0f;
    for (int i = 0; i < NB; i++) tot += partial[i];
    out[0] = tot * (1.0f / (float)NBP);
  }
}

extern "C" void kernel_launch(void* const* d_in, const int* in_sizes, int n_in,
                              void* d_out, int out_size, void* d_ws, size_t ws_size,
                              hipStream_t stream) {
  const float* em     = (const float*)d_in[0];
  const int*   elen   = (const int*)d_in[1];
  const int*   labels = (const int*)d_in[2];
  const int*   llen   = (const int*)d_in[3];
  float* out = (float*)d_out;
  char* ws = (char*)d_ws;
  int*   tok  = (int*)ws;                                  // 500*800*4 = 1.6 MB
  float* lp   = (float*)(ws + (size_t)NT * NBP * 4);       // 1.6 MB
  float* wer  = (float*)(ws + (size_t)2 * NT * NBP * 4);   // 3.2 KB
  float* logp = (float*)(ws + (size_t)2 * NT * NBP * 4 + NBP * 4);

  k_sample<<<dim3(NB, NT), dim3(256), 0, stream>>>(em, elen, tok, lp);
  k_dp<<<dim3((NBP + 63) / 64), dim3(64), 0, stream>>>(tok, lp, elen, labels, llen, wer, logp);
  k_final<<<dim3(1), dim3(512), 0, stream>>>(wer, logp, out);
}

// Round 2
// 270.661 us; speedup vs baseline: 1.4084x; 1.4084x over previous
//
#include <hip/hip_runtime.h>
#include <stdint.h>

#define NB 8
#define NP 100
#define NT 500
#define NV 128
#define NBP 800   // NB*NP
#define TILE 8

// ---------------- Threefry-2x32, key = (0,1) (jax.random.key(1)) ----------------
__device__ __forceinline__ void threefry01(uint32_t x0, uint32_t x1,
                                           uint32_t& o0, uint32_t& o1) {
  const uint32_t k0 = 0u, k1 = 1u;
  const uint32_t k2 = 0x1BD11BDAu ^ k0 ^ k1;  // 0x1BD11BDB
  x0 += k0; x1 += k1;
#define TF_R(r) { x0 += x1; x1 = (x1 << (r)) | (x1 >> (32 - (r))); x1 ^= x0; }
  TF_R(13) TF_R(15) TF_R(26) TF_R(6)
  x0 += k1; x1 += k2 + 1u;
  TF_R(17) TF_R(29) TF_R(16) TF_R(24)
  x0 += k2; x1 += k0 + 2u;
  TF_R(13) TF_R(15) TF_R(26) TF_R(6)
  x0 += k0; x1 += k1 + 3u;
  TF_R(17) TF_R(29) TF_R(16) TF_R(24)
  x0 += k1; x1 += k2 + 4u;
  TF_R(13) TF_R(15) TF_R(26) TF_R(6)
  x0 += k2; x1 += k0 + 5u;
#undef TF_R
  o0 = x0; o1 = x1;
}

// bits -> uniform(1e-6, 1-1e-6) exactly as jax._src.random._uniform (f32)
// (expression kept byte-identical to the round that passed — do not perturb)
__device__ __forceinline__ float bits_to_u(uint32_t bits) {
  const float minv = 1e-6f;
  const float maxv = (float)(1.0 - 1e-6);
  const float span = maxv - minv;
  float f = __uint_as_float((bits >> 9) | 0x3f800000u) - 1.0f;
  return fmaxf(minv, f * span + minv);
}

__device__ __forceinline__ float gumbel_from_bits(uint32_t bits) {
  float u = bits_to_u(bits);
  return -__logf(-__logf(u));   // precision only affects argmax near-ties
}

// monotone f32 -> u32 map for unsigned-max reduction
__device__ __forceinline__ uint32_t sortable(float f) {
  uint32_t b = __float_as_uint(f);
  return b ^ ((uint32_t)((int32_t)b >> 31) | 0x80000000u);
}

// ---------------- Kernel 1: Gumbel sampling + argmax over V=128 ----------------
// grid (NB, NT), block 256 (4 waves); wave w handles p = w, w+4, ... (25 each)
// writes tl[t*NBP+bp] = {token, bits(emissions[token])}
__global__ __launch_bounds__(256) void k_sample(
    const float* __restrict__ em, const int* __restrict__ elen,
    int2* __restrict__ tl) {
  const int b = blockIdx.x;
  const int t = blockIdx.y;
  if (t >= elen[b]) return;  // frames beyond length are never consumed
  __shared__ float e[NV];
  const int tid = threadIdx.x;
  if (tid < NV) e[tid] = em[(b * NT + t) * NV + tid];
  __syncthreads();
  const int wave = tid >> 6, lane = tid & 63;
  const float e_lo = e[lane], e_hi = e[lane + 64];
  for (int p = wave; p < NP; p += 4) {
    const uint32_t base = (uint32_t)(((b * NP + p) * NT + t) * NV);
    // partitionable threefry: bits[i] = low output of threefry(key, i>>32, i)
    uint32_t d0, ra, d1, rb;
    threefry01(0u, base + (uint32_t)lane, d0, ra);
    threefry01(0u, base + (uint32_t)lane + 64u, d1, rb);
    const float v0 = fmaf(e_lo, 0.5f, gumbel_from_bits(ra));
    const float v1 = fmaf(e_hi, 0.5f, gumbel_from_bits(rb));
    const uint32_t s0 = sortable(v0), s1 = sortable(v1);
    uint32_t mx = s0 > s1 ? s0 : s1;
    for (int off = 1; off < 64; off <<= 1) {
      uint32_t o = (uint32_t)__shfl_xor((int)mx, off);
      mx = o > mx ? o : mx;
    }
    // first-index tiebreak: any lo index beats any hi index
    int bi;
    const unsigned long long mlo = __ballot(s0 == mx);
    if (mlo) bi = (int)__builtin_ctzll(mlo);
    else {
      const unsigned long long mhi = __ballot(s1 == mx);
      bi = (int)__builtin_ctzll(mhi) + 64;
    }
    if (lane == 0) {
      tl[t * NBP + (b * NP + p)] = make_int2(bi, __float_as_int(e[bi]));
    }
  }
}

// ---------------- Kernel 2: CTC collapse + Myers bit-parallel edit distance ----
// one lane per path; 13 blocks x 64. T tiled by 8, distance-2 prefetch,
// batched peq LDS reads per tile. Serial Myers chain is the residual floor.
__global__ __launch_bounds__(64) void k_dp(
    const int2* __restrict__ tl,
    const int* __restrict__ elen, const int* __restrict__ labels,
    const int* __restrict__ llen,
    float* __restrict__ wer, float* __restrict__ logp_out) {
  __shared__ unsigned long long peq[2][NV][2];  // [b_local][token][word], 4 KB
  const int lane = threadIdx.x;
  const int bp = blockIdx.x * 64 + lane;
  const int bbase = (blockIdx.x * 64) / NP;
  for (int i = lane; i < 2 * NV * 2; i += 64) ((unsigned long long*)peq)[i] = 0ull;
  __syncthreads();
  if (lane < 2) {
    const int bb = bbase + lane;
    if (bb < NB) {
      const int mm = llen[bb];
      for (int i = 0; i < mm; i++) {
        const int c = labels[bb * 100 + i];  // L == 100
        peq[lane][c][i >> 6] |= (1ull << (i & 63));
      }
    }
  }
  __syncthreads();
  const bool active = (bp < NBP);
  const int bpc = active ? bp : (NBP - 1);
  const int b = bpc / NP;
  const int blocal = b - bbase;
  const int myel = elen[b];
  const int m = llen[b];  // ref_len in [80,100]
  int tmax = myel;
  for (int off = 1; off < 64; off <<= 1) {
    int o = __shfl_xor(tmax, off);
    tmax = o > tmax ? o : tmax;
  }
  const int ntiles = (tmax + TILE - 1) / TILE;  // >= 50 always

  unsigned long long Pv0 = ~0ull, Pv1 = ~0ull, Mv0 = 0ull, Mv1 = 0ull;
  int score = m;
  const int hw = (m - 1) >> 6;
  const unsigned long long hmask = 1ull << ((m - 1) & 63);
  double logp = 0.0;
  int prev = -1;

  int2 buf[2][TILE];
#pragma unroll
  for (int i = 0; i < TILE; i++) buf[0][i] = tl[i * NBP + bpc];
#pragma unroll
  for (int i = 0; i < TILE; i++) buf[1][i] = tl[(TILE + i) * NBP + bpc];

  for (int tile = 0; tile < ntiles; tile++) {
    int cc[TILE]; float ll[TILE];
#pragma unroll
    for (int i = 0; i < TILE; i++) {
      cc[i] = buf[tile & 1][i].x;
      ll[i] = __int_as_float(buf[tile & 1][i].y);
    }
    // batched, independent LDS reads (index clamped; garbage beyond myel unused)
    unsigned long long eq0[TILE], eq1[TILE];
#pragma unroll
    for (int i = 0; i < TILE; i++) {
      const int c = cc[i] & 127;
      eq0[i] = peq[blocal][c][0];
      eq1[i] = peq[blocal][c][1];
    }
    // distance-2 prefetch into the buffer we just drained
    if (tile + 2 < ntiles) {
#pragma unroll
      for (int i = 0; i < TILE; i++) {
        int t = (tile + 2) * TILE + i;
        t = t < NT ? t : NT - 1;
        buf[tile & 1][i] = tl[t * NBP + bpc];
      }
    }
#pragma unroll
    for (int i = 0; i < TILE; i++) {
      const int t = tile * TILE + i;
      const bool valid = (t < myel);
      const int c = cc[i];
      const bool kept = valid && (c != 0) && (c != prev);
      if (valid) { logp += (double)ll[i]; prev = c; }
      if (kept) {
        const unsigned long long Eq0 = eq0[i], Eq1 = eq1[i];
        const unsigned long long Xv0 = Eq0 | Mv0, Xv1 = Eq1 | Mv1;
        const unsigned long long EP0 = Eq0 & Pv0, EP1 = Eq1 & Pv1;
        const unsigned long long sA = EP0 + Pv0;
        const unsigned long long sB = EP1 + Pv1 + (sA < EP0 ? 1ull : 0ull);
        const unsigned long long Xh0 = (sA ^ Pv0) | Eq0;
        const unsigned long long Xh1 = (sB ^ Pv1) | Eq1;
        const unsigned long long Ph0 = Mv0 | ~(Xh0 | Pv0);
        const unsigned long long Ph1 = Mv1 | ~(Xh1 | Pv1);
        const unsigned long long Mh0 = Pv0 & Xh0, Mh1 = Pv1 & Xh1;
        score += (int)(((hw ? Ph1 : Ph0) & hmask) != 0);
        score -= (int)(((hw ? Mh1 : Mh0) & hmask) != 0);
        const unsigned long long nPh1 = (Ph1 << 1) | (Ph0 >> 63);
        const unsigned long long nPh0 = (Ph0 << 1) | 1ull;   // dp[i][0] = i boundary
        const unsigned long long nMh1 = (Mh1 << 1) | (Mh0 >> 63);
        const unsigned long long nMh0 = (Mh0 << 1);
        Pv0 = nMh0 | ~(Xv0 | nPh0);
        Pv1 = nMh1 | ~(Xv1 | nPh1);
        Mv0 = nPh0 & Xv0;
        Mv1 = nPh1 & Xv1;
      }
    }
  }
  if (active) { wer[bp] = (float)score; logp_out[bp] = (float)logp; }
}

// ---------------- Kernel 3: per-b softmax over P, expected WER, mean -----------
__global__ __launch_bounds__(512) void k_final(
    const float* __restrict__ wer, const float* __restrict__ logp,
    float* __restrict__ out) {
  __shared__ float partial[NB];
  const int w = threadIdx.x >> 6, lane = threadIdx.x & 63;
  const int base = w * NP;
  float l0 = (lane < NP) ? logp[base + lane] : -1e30f;
  float l1 = (lane + 64 < NP) ? logp[base + lane + 64] : -1e30f;
  float mx = fmaxf(l0, l1);
  for (int off = 1; off < 64; off <<= 1) mx = fmaxf(mx, __shfl_xor(mx, off));
  const float e0 = (lane < NP) ? __expf(l0 - mx) : 0.0f;
  const float e1 = (lane + 64 < NP) ? __expf(l1 - mx) : 0.0f;
  const float w0 = (lane < NP) ? wer[base + lane] : 0.0f;
  const float w1 = (lane + 64 < NP) ? wer[base + lane + 64] : 0.0f;
  float s = e0 + e1;
  float a = e0 * w0 + e1 * w1;
  for (int off = 1; off < 64; off <<= 1) {
    s += __shfl_xor(s, off);
    a += __shfl_xor(a, off);
  }
  if (lane == 0) partial[w] = a / s;
  __syncthreads();
  if (threadIdx.x == 0) {
    float tot = 0.0f;
    for (int i = 0; i < NB; i++) tot += partial[i];
    out[0] = tot * (1.0f / (float)NBP);
  }
}

extern "C" void kernel_launch(void* const* d_in, const int* in_sizes, int n_in,
                              void* d_out, int out_size, void* d_ws, size_t ws_size,
                              hipStream_t stream) {
  const float* em     = (const float*)d_in[0];
  const int*   elen   = (const int*)d_in[1];
  const int*   labels = (const int*)d_in[2];
  const int*   llen   = (const int*)d_in[3];
  float* out = (float*)d_out;
  char* ws = (char*)d_ws;
  int2*  tlb  = (int2*)ws;                                  // 500*800*8 = 3.2 MB
  float* wer  = (float*)(ws + (size_t)NT * NBP * 8);        // 3.2 KB
  float* logp = (float*)(ws + (size_t)NT * NBP * 8 + NBP * 4);

  k_sample<<<dim3(NB, NT), dim3(256), 0, stream>>>(em, elen, tlb);
  k_dp<<<dim3((NBP + 63) / 64), dim3(64), 0, stream>>>(tlb, elen, labels, llen, wer, logp);
  k_final<<<dim3(1), dim3(512), 0, stream>>>(wer, logp, out);
}